// Round 1
// baseline (1305.097 us; speedup 1.0000x reference)
//
#include <hip/hip_runtime.h>
#include <math.h>

#define LL 2048
#define MM 12
#define DD 128
#define TP 256   // T

// ---------------- embedding: strided conv1d (stride 8, K=16, pad 4/4) ----------------
__global__ __launch_bounds__(256) void k_emb(const float* __restrict__ inp, const float* __restrict__ ew,
                                             const float* __restrict__ eb, float* __restrict__ xe) {
  int sig = blockIdx.x;
  int b = sig / MM, m = sig % MM;
  __shared__ float xs[LL];
  const float* ib = inp + (size_t)b * LL * MM + m;
  for (int i = threadIdx.x; i < LL; i += 256) xs[i] = ib[(size_t)i * MM];
  __syncthreads();
  int t = threadIdx.x;
  int l0 = t * 8 - 4;
  float xv[16];
#pragma unroll
  for (int p = 0; p < 16; ++p) {
    int l = l0 + p;
    xv[p] = (l >= 0 && l < LL) ? xs[l] : 0.0f;
  }
  float* out = xe + (size_t)sig * DD * TP + t;
  for (int d = 0; d < DD; ++d) {
    float acc = eb[d];
#pragma unroll
    for (int p = 0; p < 16; ++p) acc += xv[p] * ew[d * 16 + p];
    out[(size_t)d * TP] = acc;
  }
}

// ---------------- block: depthwise conv K=5 + exact GELU ----------------
__global__ __launch_bounds__(256) void k_dwgelu(const float* __restrict__ u, const float* __restrict__ dww,
                                                const float* __restrict__ dwb, float* __restrict__ v) {
  int sig = blockIdx.x >> 4;
  int d0 = (blockIdx.x & 15) * 8;
  __shared__ float us[8][TP];
  const float* ub = u + (size_t)sig * DD * TP + (size_t)d0 * TP;
  for (int i = threadIdx.x; i < 8 * TP; i += 256) us[i >> 8][i & 255] = ub[i];
  __syncthreads();
  int t = threadIdx.x;
  float* vb = v + (size_t)sig * DD * TP + (size_t)d0 * TP + t;
#pragma unroll
  for (int di = 0; di < 8; ++di) {
    int d = d0 + di;
    float acc = dwb[d];
#pragma unroll
    for (int k = 0; k < 5; ++k) {
      int tt = t - 2 + k;
      if (tt >= 0 && tt < TP) acc += us[di][tt] * dww[d * 5 + k];
    }
    vb[(size_t)di * TP] = 0.5f * acc * (1.0f + erff(acc * 0.70710678118654752f));
  }
}

// ---------------- block: pointwise 128x128 matmul, in-place w over v, + column-sum ----------------
__global__ __launch_bounds__(256) void k_pw(float* __restrict__ vw, const float* __restrict__ pw,
                                            const float* __restrict__ pwb, float* __restrict__ sbuf) {
  int sig = blockIdx.x >> 2;
  int t0 = (blockIdx.x & 3) * 64;
  __shared__ float vt[32][64];
  __shared__ float pwT[32][132];
  __shared__ float sred[128][8];
  int tid = threadIdx.x;
  int eg = tid >> 3, tg = tid & 7;
  int e0 = eg * 4, tb = tg * 8;
  float acc[4][8];
#pragma unroll
  for (int j = 0; j < 4; ++j)
#pragma unroll
    for (int i = 0; i < 8; ++i) acc[j][i] = 0.0f;
  float* vbase = vw + (size_t)sig * DD * TP + t0;
  for (int dc = 0; dc < 4; ++dc) {
    int d0 = dc * 32;
    __syncthreads();
    for (int idx = tid; idx < 32 * 64; idx += 256) {
      int di = idx >> 6, tt = idx & 63;
      vt[di][tt] = vbase[(size_t)(d0 + di) * TP + tt];
    }
    for (int idx = tid; idx < 32 * 128; idx += 256) {
      int di = idx & 31, e = idx >> 5;
      pwT[di][e] = pw[e * DD + d0 + di];
    }
    __syncthreads();
#pragma unroll
    for (int di = 0; di < 32; ++di) {
      float4 p4 = *(const float4*)&pwT[di][e0];
      float4 va = *(const float4*)&vt[di][tb];
      float4 vb4 = *(const float4*)&vt[di][tb + 4];
      float pv[4] = {p4.x, p4.y, p4.z, p4.w};
      float vv[8] = {va.x, va.y, va.z, va.w, vb4.x, vb4.y, vb4.z, vb4.w};
#pragma unroll
      for (int j = 0; j < 4; ++j)
#pragma unroll
        for (int i = 0; i < 8; ++i) acc[j][i] += pv[j] * vv[i];
    }
  }
#pragma unroll
  for (int j = 0; j < 4; ++j) {
    float bb = pwb[e0 + j];
    float ssum = 0.0f;
#pragma unroll
    for (int i = 0; i < 8; ++i) { acc[j][i] += bb; ssum += acc[j][i]; }
    sred[e0 + j][tg] = ssum;
  }
#pragma unroll
  for (int j = 0; j < 4; ++j) {
    float4 w0 = {acc[j][0], acc[j][1], acc[j][2], acc[j][3]};
    float4 w1 = {acc[j][4], acc[j][5], acc[j][6], acc[j][7]};
    *(float4*)&vbase[(size_t)(e0 + j) * TP + tb] = w0;
    *(float4*)&vbase[(size_t)(e0 + j) * TP + tb + 4] = w1;
  }
  __syncthreads();
  if (tid < 128) {
    float tot = 0.0f;
#pragma unroll
    for (int g = 0; g < 8; ++g) tot += sred[tid][g];
    atomicAdd(&sbuf[sig * DD + tid], tot);
  }
}

// ---------------- block: SE gate ----------------
__global__ __launch_bounds__(128) void k_se(const float* __restrict__ sbuf, const float* __restrict__ w1,
                                            const float* __restrict__ b1, const float* __restrict__ w2,
                                            const float* __restrict__ b2, float* __restrict__ abuf) {
  int sig = blockIdx.x;
  __shared__ float sm[128];
  __shared__ float hh[32];
  int tid = threadIdx.x;
  sm[tid] = sbuf[sig * 128 + tid] * (1.0f / 256.0f);
  __syncthreads();
  if (tid < 32) {
    float acc = b1[tid];
    for (int d = 0; d < 128; ++d) acc += w1[tid * 128 + d] * sm[d];
    hh[tid] = fmaxf(acc, 0.0f);
  }
  __syncthreads();
  float acc = b2[tid];
#pragma unroll
  for (int r = 0; r < 32; ++r) acc += w2[tid * 32 + r] * hh[r];
  abuf[sig * 128 + tid] = 1.0f / (1.0f + expf(-acc));
}

// ---------------- block: u += w * a ----------------
__global__ __launch_bounds__(256) void k_upd(float* __restrict__ u, const float* __restrict__ w,
                                             const float* __restrict__ abuf) {
  size_t i = (size_t)blockIdx.x * 256 + threadIdx.x;  // float4 index
  int sig = (int)(i >> 13);
  int d = (int)((i >> 6) & 127);
  float a = abuf[sig * 128 + d];
  float4 uv = ((float4*)u)[i];
  float4 wv = ((const float4*)w)[i];
  uv.x += wv.x * a; uv.y += wv.y * a; uv.z += wv.z * a; uv.w += wv.w * a;
  ((float4*)u)[i] = uv;
}

// ---------------- mean over M + layout change to (b,t,d) ----------------
__global__ __launch_bounds__(256) void k_reduce(const float* __restrict__ xe, float* __restrict__ xe2) {
  size_t i = (size_t)blockIdx.x * 256 + threadIdx.x;  // over 64*128*256
  int t = (int)(i & 255);
  int d = (int)((i >> 8) & 127);
  int b = (int)(i >> 15);
  float acc = 0.0f;
  const float* base = xe + (size_t)b * 12 * 32768 + d * 256 + t;
#pragma unroll
  for (int m = 0; m < 12; ++m) acc += base[(size_t)m * 32768];
  xe2[(size_t)b * 32768 + t * 128 + d] = acc * (1.0f / 12.0f);
}

// ---------------- small transpose dst[c*rows+r] = src[r*cols+c] ----------------
__global__ __launch_bounds__(256) void k_transpose(const float* __restrict__ src, float* __restrict__ dst,
                                                   int rows, int cols) {
  int i = blockIdx.x * 256 + threadIdx.x;
  if (i < rows * cols) {
    int r = i / cols, c = i % cols;
    dst[c * rows + r] = src[i];
  }
}

// ---------------- mamba: in-projection xz[b,t,e] = sum_d in_w[e,d] x[b,t,d] ----------------
__global__ __launch_bounds__(256) void k_inproj(const float* __restrict__ xe2, const float* __restrict__ inwT,
                                                float* __restrict__ xz) {
  int b = blockIdx.x >> 4;
  int t0 = (blockIdx.x & 15) * 16;
  __shared__ float xT[128][16];
  int tid = threadIdx.x;
  for (int idx = tid; idx < 2048; idx += 256) {
    int t = idx >> 7, d = idx & 127;
    xT[d][t] = xe2[(size_t)b * 32768 + (size_t)(t0 + t) * 128 + d];
  }
  __syncthreads();
  int eg = tid >> 1, tg = tid & 1;
  int e0 = eg * 4, ts = tg * 8;
  float acc[4][8];
#pragma unroll
  for (int j = 0; j < 4; ++j)
#pragma unroll
    for (int i = 0; i < 8; ++i) acc[j][i] = 0.0f;
#pragma unroll 4
  for (int d = 0; d < 128; ++d) {
    float4 wv = *(const float4*)&inwT[d * 512 + e0];
    float4 xa = *(const float4*)&xT[d][ts];
    float4 xb = *(const float4*)&xT[d][ts + 4];
    float xv[8] = {xa.x, xa.y, xa.z, xa.w, xb.x, xb.y, xb.z, xb.w};
    float wvv[4] = {wv.x, wv.y, wv.z, wv.w};
#pragma unroll
    for (int j = 0; j < 4; ++j)
#pragma unroll
      for (int i = 0; i < 8; ++i) acc[j][i] += wvv[j] * xv[i];
  }
#pragma unroll
  for (int i = 0; i < 8; ++i) {
    float4 o = {acc[0][i], acc[1][i], acc[2][i], acc[3][i]};
    *(float4*)&xz[(size_t)b * 256 * 512 + (size_t)(t0 + ts + i) * 512 + e0] = o;
  }
}

// ---------------- mamba: causal depthwise conv (K=4) + SiLU ----------------
__global__ __launch_bounds__(256) void k_convsilu(const float* __restrict__ xz, const float* __restrict__ cw,
                                                  const float* __restrict__ cb, float* __restrict__ xc) {
  size_t i = (size_t)blockIdx.x * 256 + threadIdx.x;  // 64*256*256
  int c = (int)(i & 255);
  int t = (int)((i >> 8) & 255);
  int b = (int)(i >> 16);
  const float* zb = xz + (size_t)b * 256 * 512 + c;
  float4 w4 = *(const float4*)&cw[c * 4];
  float wv[4] = {w4.x, w4.y, w4.z, w4.w};
  float acc = cb[c];
#pragma unroll
  for (int k = 0; k < 4; ++k) {
    int tt = t - 3 + k;
    if (tt >= 0) acc += zb[(size_t)tt * 512] * wv[k];
  }
  xc[i] = acc / (1.0f + expf(-acc));
}

// ---------------- mamba: x-projection (40 x 256) ----------------
__global__ __launch_bounds__(256) void k_xproj(const float* __restrict__ xc, const float* __restrict__ xw,
                                               float* __restrict__ dbl) {
  int b = blockIdx.x >> 3;
  int t0 = (blockIdx.x & 7) * 32;
  __shared__ float xT[256][33];
  int tid = threadIdx.x;
  for (int idx = tid; idx < 32 * 256; idx += 256) {
    int t = idx >> 8, c = idx & 255;
    xT[c][t] = xc[(size_t)b * 65536 + (size_t)(t0 + t) * 256 + c];
  }
  __syncthreads();
  int t = tid & 31, k0 = tid >> 5;
  for (int k = k0; k < 40; k += 8) {
    float acc = 0.0f;
    for (int c = 0; c < 256; ++c) acc += xw[k * 256 + c] * xT[c][t];
    dbl[(size_t)b * 256 * 40 + (size_t)(t0 + t) * 40 + k] = acc;
  }
}

// ---------------- mamba: dt = softplus(dt_w @ dtr + dt_b) ----------------
__global__ __launch_bounds__(256) void k_dt(const float* __restrict__ dbl, const float* __restrict__ dtw,
                                            const float* __restrict__ dtb, float* __restrict__ dt) {
  size_t i = (size_t)blockIdx.x * 256 + threadIdx.x;  // 64*256*256
  int c = (int)(i & 255);
  size_t bt = i >> 8;
  const float* dr = dbl + bt * 40;
  float4 wa = *(const float4*)&dtw[c * 8];
  float4 wb = *(const float4*)&dtw[c * 8 + 4];
  float acc = dtb[c];
  acc += wa.x * dr[0] + wa.y * dr[1] + wa.z * dr[2] + wa.w * dr[3]
       + wb.x * dr[4] + wb.y * dr[5] + wb.z * dr[6] + wb.w * dr[7];
  dt[i] = (acc > 20.0f) ? acc : log1pf(expf(acc));
}

// ---------------- mamba: selective scan (16 states per channel across lanes) ----------------
__global__ __launch_bounds__(256) void k_scan(const float* __restrict__ dt, const float* __restrict__ xc,
                                              const float* __restrict__ dbl, const float* __restrict__ Alog,
                                              float* __restrict__ ys) {
  int b = blockIdx.x >> 4;
  int c0 = (blockIdx.x & 15) * 16;
  int tid = threadIdx.x;
  int ci = tid >> 4, s = tid & 15;
  int c = c0 + ci;
  float A = -expf(Alog[c * 16 + s]);
  float h = 0.0f;
  const float* dtp = dt + (size_t)b * 65536 + c;
  const float* xcp = xc + (size_t)b * 65536 + c;
  const float* dbp = dbl + (size_t)b * 10240;
  float* yp = ys + (size_t)b * 65536 + c;
  for (int t = 0; t < 256; ++t) {
    float dtv = dtp[(size_t)t * 256];
    float xcv = xcp[(size_t)t * 256];
    float Bv = dbp[t * 40 + 8 + s];
    float Cv = dbp[t * 40 + 24 + s];
    h = __expf(dtv * A) * h + dtv * Bv * xcv;
    float p = h * Cv;
    p += __shfl_xor(p, 1, 64);
    p += __shfl_xor(p, 2, 64);
    p += __shfl_xor(p, 4, 64);
    p += __shfl_xor(p, 8, 64);
    if (s == 0) yp[(size_t)t * 256] = p;
  }
}

// ---------------- mamba: y = (ys + D*xc) * silu(z) ----------------
__global__ __launch_bounds__(256) void k_yfin(const float* __restrict__ ys, const float* __restrict__ xc,
                                              const float* __restrict__ xz, const float* __restrict__ Dp,
                                              float* __restrict__ y) {
  size_t i = (size_t)blockIdx.x * 256 + threadIdx.x;  // 64*256*256
  int c = (int)(i & 255);
  size_t bt = i >> 8;
  float z = xz[bt * 512 + 256 + c];
  float sz = z / (1.0f + expf(-z));
  y[i] = (ys[i] + Dp[c] * xc[i]) * sz;
}

// ---------------- mamba: out-projection + residual + LayerNorm (in place on xe2) ----------------
__global__ __launch_bounds__(256) void k_outln(const float* __restrict__ y, const float* __restrict__ owT,
                                               float* __restrict__ xe2, const float* __restrict__ g,
                                               const float* __restrict__ bb) {
  int b = blockIdx.x >> 5;
  int t0 = (blockIdx.x & 31) * 8;
  __shared__ float yl[8][256];
  __shared__ float rl[8][129];
  __shared__ float mus[8], rvs[8];
  int tid = threadIdx.x;
  for (int idx = tid; idx < 8 * 256; idx += 256) {
    int t = idx >> 8, c = idx & 255;
    yl[t][c] = y[(size_t)b * 65536 + (size_t)(t0 + t) * 256 + c];
  }
  __syncthreads();
  int d = tid & 127, tg = tid >> 7;
  float acc[4] = {0.f, 0.f, 0.f, 0.f};
  for (int e = 0; e < 256; ++e) {
    float w = owT[e * 128 + d];
#pragma unroll
    for (int i = 0; i < 4; ++i) acc[i] += w * yl[tg * 4 + i][e];
  }
#pragma unroll
  for (int i = 0; i < 4; ++i) {
    int t = tg * 4 + i;
    float r = xe2[(size_t)b * 32768 + (size_t)(t0 + t) * 128 + d] + acc[i];
    rl[t][d] = r;
  }
  __syncthreads();
  int rt = tid >> 5, j = tid & 31;
  float s1 = 0.f, s2 = 0.f;
#pragma unroll
  for (int q = 0; q < 4; ++q) {
    float vv = rl[rt][j + q * 32];
    s1 += vv; s2 += vv * vv;
  }
#pragma unroll
  for (int m = 1; m <= 16; m <<= 1) {
    s1 += __shfl_xor(s1, m, 64);
    s2 += __shfl_xor(s2, m, 64);
  }
  if (j == 0) {
    float mu = s1 * (1.0f / 128.0f);
    float var = s2 * (1.0f / 128.0f) - mu * mu;
    mus[rt] = mu;
    rvs[rt] = rsqrtf(var + 1e-5f);
  }
  __syncthreads();
#pragma unroll
  for (int i = 0; i < 4; ++i) {
    int t = tg * 4 + i;
    float val = (rl[t][d] - mus[t]) * rvs[t] * g[d] + bb[d];
    xe2[(size_t)b * 32768 + (size_t)(t0 + t) * 128 + d] = val;
  }
}

// ---------------- xflat transpose: out[b, d*256+t] = xe2[b, t*128+d] ----------------
__global__ __launch_bounds__(256) void k_xflat(const float* __restrict__ xe2, float* __restrict__ out) {
  int b = blockIdx.x >> 5;
  int blk = blockIdx.x & 31;
  int t0 = (blk >> 2) * 32, d0 = (blk & 3) * 32;
  __shared__ float tile[32][33];
  int tid = threadIdx.x;
#pragma unroll
  for (int q = 0; q < 4; ++q) {
    int t = (tid >> 5) + q * 8, dd = tid & 31;
    tile[t][dd] = xe2[(size_t)b * 32768 + (size_t)(t0 + t) * 128 + d0 + dd];
  }
  __syncthreads();
#pragma unroll
  for (int q = 0; q < 4; ++q) {
    int dd = (tid >> 5) + q * 8, t = tid & 31;
    out[(size_t)b * 32768 + (size_t)(d0 + dd) * 256 + t0 + t] = tile[t][dd];
  }
}

// ---------------- final FC: pred[b,c] = xflat[b,:] . fc_w[c,:] + fc_b[c] ----------------
__global__ __launch_bounds__(256) void k_fc(const float* __restrict__ xflat, const float* __restrict__ fw,
                                            const float* __restrict__ fb, float* __restrict__ pred) {
  int b = blockIdx.x;
  int tid = threadIdx.x;
  float acc[18];
#pragma unroll
  for (int c = 0; c < 18; ++c) acc[c] = 0.0f;
  const float* xb = xflat + (size_t)b * 32768;
  for (int i = tid * 4; i < 32768; i += 1024) {
    float4 xv = *(const float4*)&xb[i];
#pragma unroll
    for (int c = 0; c < 18; ++c) {
      float4 wv = *(const float4*)&fw[(size_t)c * 32768 + i];
      acc[c] += xv.x * wv.x + xv.y * wv.y + xv.z * wv.z + xv.w * wv.w;
    }
  }
  __shared__ float red[256];
  for (int c = 0; c < 18; ++c) {
    red[tid] = acc[c];
    __syncthreads();
    for (int off = 128; off > 0; off >>= 1) {
      if (tid < off) red[tid] += red[tid + off];
      __syncthreads();
    }
    if (tid == 0) pred[b * 18 + c] = red[0] + fb[c];
    __syncthreads();
  }
}

extern "C" void kernel_launch(void* const* d_in, const int* in_sizes, int n_in,
                              void* d_out, int out_size, void* d_ws, size_t ws_size,
                              hipStream_t stream) {
  (void)in_sizes; (void)n_in; (void)out_size; (void)ws_size;
  const float* inp    = (const float*)d_in[0];
  const float* emb_w  = (const float*)d_in[1];
  const float* emb_b  = (const float*)d_in[2];
  const float* dw_w   = (const float*)d_in[3];
  const float* dw_b   = (const float*)d_in[4];
  const float* pw_w   = (const float*)d_in[5];
  const float* pw_b   = (const float*)d_in[6];
  const float* se_w1  = (const float*)d_in[7];
  const float* se_b1  = (const float*)d_in[8];
  const float* se_w2  = (const float*)d_in[9];
  const float* se_b2  = (const float*)d_in[10];
  const float* in_w   = (const float*)d_in[11];
  const float* conv_w = (const float*)d_in[12];
  const float* conv_b = (const float*)d_in[13];
  const float* xp_w   = (const float*)d_in[14];
  const float* dt_w   = (const float*)d_in[15];
  const float* dt_b   = (const float*)d_in[16];
  const float* Alog   = (const float*)d_in[17];
  const float* Dp     = (const float*)d_in[18];
  const float* out_w  = (const float*)d_in[19];
  const float* ln_g   = (const float*)d_in[20];
  const float* ln_b   = (const float*)d_in[21];
  const float* fc_w   = (const float*)d_in[22];
  const float* fc_b   = (const float*)d_in[23];

  char* ws = (char*)d_ws;
  float* bufA = (float*)ws;                    // 25165824 floats (xe)
  float* bufB = (float*)(ws + 100663296);      // 25165824 floats (v/w)
  float* sbuf = (float*)(ws + 201326592);      // 98304 floats
  float* abuf = sbuf + 98304;                  // 98304 floats
  // mamba-stage carve (bufA/bufB free after k_reduce):
  float* xz   = bufA;                 // 8388608
  float* xc   = bufA + 8388608;       // 4194304
  float* dtb  = bufA + 12582912;      // 4194304
  float* ysb  = bufA + 16777216;      // 4194304
  float* yb   = bufA + 20971520;      // 4194304
  float* xe2  = bufB;                 // 2097152
  float* dbl  = bufB + 2097152;       // 655360
  float* inwT = bufB + 2752512;       // 65536
  float* owT  = bufB + 2818048;       // 32768

  float* xflat = (float*)d_out;
  float* pred  = xflat + (size_t)64 * 32768;

  k_emb<<<768, 256, 0, stream>>>(inp, emb_w, emb_b, bufA);

  for (int i = 0; i < 3; ++i) {
    k_dwgelu<<<12288, 256, 0, stream>>>(bufA, dw_w + i * 640, dw_b + i * 128, bufB);
    hipMemsetAsync(sbuf, 0, 98304 * sizeof(float), stream);
    k_pw<<<3072, 256, 0, stream>>>(bufB, pw_w + i * 16384, pw_b + i * 128, sbuf);
    k_se<<<768, 128, 0, stream>>>(sbuf, se_w1 + i * 4096, se_b1 + i * 32,
                                  se_w2 + i * 4096, se_b2 + i * 128, abuf);
    k_upd<<<24576, 256, 0, stream>>>(bufA, bufB, abuf);
  }

  k_reduce<<<8192, 256, 0, stream>>>(bufA, xe2);

  for (int i = 0; i < 2; ++i) {
    k_transpose<<<256, 256, 0, stream>>>(in_w + i * 65536, inwT, 512, 128);
    k_transpose<<<128, 256, 0, stream>>>(out_w + i * 32768, owT, 128, 256);
    k_inproj<<<1024, 256, 0, stream>>>(xe2, inwT, xz);
    k_convsilu<<<16384, 256, 0, stream>>>(xz, conv_w + i * 1024, conv_b + i * 256, xc);
    k_xproj<<<512, 256, 0, stream>>>(xc, xp_w + i * 10240, dbl);
    k_dt<<<16384, 256, 0, stream>>>(dbl, dt_w + i * 2048, dt_b + i * 256, dtb);
    k_scan<<<1024, 256, 0, stream>>>(dtb, xc, dbl, Alog + i * 4096, ysb);
    k_yfin<<<16384, 256, 0, stream>>>(ysb, xc, xz, Dp + i * 256, yb);
    k_outln<<<2048, 256, 0, stream>>>(yb, owT, xe2, ln_g + i * 128, ln_b + i * 128);
  }

  k_xflat<<<2048, 256, 0, stream>>>(xe2, xflat);
  k_fc<<<64, 256, 0, stream>>>(xflat, fc_w, fc_b, pred);
}